// Round 1
// baseline (842.123 us; speedup 1.0000x reference)
//
#include <hip/hip_runtime.h>
#include <math.h>

// GAT 2-layer: N=100K nodes, E=1.6M edges + self loops.
// Strategy: build CSR-by-dst once (count/scan/fill), reuse for both layers.
// Per-node wave-local softmax (no float atomics).

#define WAVE 64

__device__ __forceinline__ float wave_max(float v){
  #pragma unroll
  for (int m = 1; m < 64; m <<= 1) v = fmaxf(v, __shfl_xor(v, m));
  return v;
}
__device__ __forceinline__ float wave_sum(float v){
  #pragma unroll
  for (int m = 1; m < 64; m <<= 1) v += __shfl_xor(v, m);
  return v;
}

// ---------------- CSR build ----------------

__global__ void zero_int_kernel(int* __restrict__ p, int n){
  int i = blockIdx.x * 256 + threadIdx.x;
  if (i < n) p[i] = 0;
}

__global__ void count_kernel(const int* __restrict__ dst, int* __restrict__ cnt,
                             int E, int tot){
  int i = blockIdx.x * 256 + threadIdx.x;
  if (i >= tot) return;
  int d = (i < E) ? dst[i] : (i - E);   // tail = self loops
  atomicAdd(&cnt[d], 1);
}

// block scans 1024 elements (4/thread), writes per-block exclusive + block sum
__global__ __launch_bounds__(256)
void scan_a_kernel(const int* __restrict__ cnt, int* __restrict__ offs,
                   int* __restrict__ aux, int n){
  __shared__ int ssum[256];
  int tid = threadIdx.x;
  int base = blockIdx.x * 1024;
  int idx = base + tid * 4;
  int4 v = make_int4(0,0,0,0);
  if (idx + 3 < n) v = *(const int4*)(cnt + idx);
  else {
    if (idx     < n) v.x = cnt[idx];
    if (idx + 1 < n) v.y = cnt[idx+1];
    if (idx + 2 < n) v.z = cnt[idx+2];
  }
  int s01 = v.x + v.y;
  int tsum = s01 + v.z + v.w;
  ssum[tid] = tsum;
  __syncthreads();
  #pragma unroll
  for (int d = 1; d < 256; d <<= 1){
    int x = (tid >= d) ? ssum[tid - d] : 0;
    __syncthreads();
    ssum[tid] += x;
    __syncthreads();
  }
  int excl = (tid > 0) ? ssum[tid-1] : 0;
  if (tid == 255) aux[blockIdx.x] = ssum[255];
  if (idx     < n) offs[idx]   = excl;
  if (idx + 1 < n) offs[idx+1] = excl + v.x;
  if (idx + 2 < n) offs[idx+2] = excl + s01;
  if (idx + 3 < n) offs[idx+3] = excl + s01 + v.z;
}

__global__ __launch_bounds__(256)
void scan_b_kernel(int* __restrict__ aux, int nb){
  __shared__ int ssum[256];
  int tid = threadIdx.x;
  int v = (tid < nb) ? aux[tid] : 0;
  ssum[tid] = v;
  __syncthreads();
  #pragma unroll
  for (int d = 1; d < 256; d <<= 1){
    int x = (tid >= d) ? ssum[tid - d] : 0;
    __syncthreads();
    ssum[tid] += x;
    __syncthreads();
  }
  if (tid < nb) aux[tid] = (tid > 0) ? ssum[tid-1] : 0;
}

__global__ void scan_c_kernel(int* __restrict__ offs, const int* __restrict__ aux,
                              int* __restrict__ cur, int n){
  int i = blockIdx.x * 256 + threadIdx.x;
  if (i >= n) return;
  int o = offs[i] + aux[i >> 10];
  offs[i] = o;
  cur[i]  = o;
}

__global__ void fill_kernel(const int* __restrict__ src, const int* __restrict__ dst,
                            int* __restrict__ cur, int* __restrict__ col,
                            int E, int tot){
  int i = blockIdx.x * 256 + threadIdx.x;
  if (i >= tot) return;
  int s, d;
  if (i < E){ s = src[i]; d = dst[i]; } else { s = i - E; d = s; }
  int pos = atomicAdd(&cur[d], 1);
  col[pos] = s;
}

// ---------------- GEMM1: [n,128] @ [128,128] ----------------
// 128x128 tile, 256 threads, 8x8 per thread (cols split c0 and c0+64).
__global__ __launch_bounds__(256)
void gemm1_kernel(const float* __restrict__ X, const float* __restrict__ W,
                  float* __restrict__ H, int n){
  __shared__ float xs[16][132];   // transposed: xs[k][row]
  __shared__ float ws[16][128];
  int tid = threadIdx.x;
  int rg = tid >> 4, cg = tid & 15;
  int r0 = rg * 8, c0 = cg * 4;
  int row0 = blockIdx.x * 128;
  float acc[8][8];
  #pragma unroll
  for (int i = 0; i < 8; i++)
    #pragma unroll
    for (int j = 0; j < 8; j++) acc[i][j] = 0.f;

  for (int k0 = 0; k0 < 128; k0 += 16){
    #pragma unroll
    for (int l = 0; l < 2; l++){
      int f4 = tid + l * 256;
      int kk = f4 >> 5, cq = f4 & 31;
      float4 w = *(const float4*)(W + (size_t)(k0 + kk) * 128 + cq * 4);
      *(float4*)&ws[kk][cq * 4] = w;
    }
    #pragma unroll
    for (int l = 0; l < 2; l++){
      int f4 = tid + l * 256;
      int row = f4 >> 2, kq = f4 & 3;
      float4 v = make_float4(0.f, 0.f, 0.f, 0.f);
      if (row0 + row < n)
        v = *(const float4*)(X + (size_t)(row0 + row) * 128 + k0 + kq * 4);
      xs[kq*4+0][row] = v.x; xs[kq*4+1][row] = v.y;
      xs[kq*4+2][row] = v.z; xs[kq*4+3][row] = v.w;
    }
    __syncthreads();
    #pragma unroll
    for (int k = 0; k < 16; k++){
      float4 xa = *(const float4*)&xs[k][r0];
      float4 xb = *(const float4*)&xs[k][r0 + 4];
      float4 wa = *(const float4*)&ws[k][c0];
      float4 wb = *(const float4*)&ws[k][c0 + 64];
      float xr[8] = {xa.x,xa.y,xa.z,xa.w,xb.x,xb.y,xb.z,xb.w};
      float wr[8] = {wa.x,wa.y,wa.z,wa.w,wb.x,wb.y,wb.z,wb.w};
      #pragma unroll
      for (int i = 0; i < 8; i++)
        #pragma unroll
        for (int j = 0; j < 8; j++)
          acc[i][j] = fmaf(xr[i], wr[j], acc[i][j]);
    }
    __syncthreads();
  }
  #pragma unroll
  for (int i = 0; i < 8; i++){
    int r = row0 + r0 + i;
    if (r < n){
      *(float4*)(H + (size_t)r * 128 + c0)
          = make_float4(acc[i][0], acc[i][1], acc[i][2], acc[i][3]);
      *(float4*)(H + (size_t)r * 128 + c0 + 64)
          = make_float4(acc[i][4], acc[i][5], acc[i][6], acc[i][7]);
    }
  }
}

// ---------------- att1: per (node,head) dot with att vectors ----------------
__global__ __launch_bounds__(256)
void att1_kernel(const float* __restrict__ H, const float* __restrict__ As,
                 const float* __restrict__ Ad, float* __restrict__ asrc,
                 float* __restrict__ adst, int n){
  __shared__ float sa[128], sd[128];
  int tid = threadIdx.x;
  if (tid < 128){ sa[tid] = As[tid]; sd[tid] = Ad[tid]; }
  __syncthreads();
  int t = blockIdx.x * 256 + tid;
  if (t >= n * 8) return;
  int node = t >> 3, h = t & 7;
  const float* hp = H + (size_t)node * 128 + h * 16;
  float s = 0.f, d = 0.f;
  #pragma unroll
  for (int c = 0; c < 16; c++){
    float v = hp[c];
    s = fmaf(v, sa[h * 16 + c], s);
    d = fmaf(v, sd[h * 16 + c], d);
  }
  asrc[t] = s; adst[t] = d;
}

// ---------------- agg1: wave per node, 8 heads x 16 ch ----------------
__global__ __launch_bounds__(256)
void agg1_kernel(const float* __restrict__ H, const int* __restrict__ offs,
                 const int* __restrict__ cnt, const int* __restrict__ col,
                 const float* __restrict__ asrc, const float* __restrict__ adst,
                 const float* __restrict__ bias, float* __restrict__ G, int n){
  int lane = threadIdx.x & 63;
  int node = blockIdx.x * 4 + (threadIdx.x >> 6);
  if (node >= n) return;
  int beg = offs[node], deg = cnt[node];

  // pass1: max per head; lane = (edge_slot<<3) | head
  int hA = lane & 7;
  float adA = adst[node * 8 + hA];
  float m = -INFINITY;
  for (int i = lane >> 3; i < deg; i += 8){
    int s = col[beg + i];
    float e = asrc[s * 8 + hA] + adA;
    e = e > 0.f ? e : 0.2f * e;
    m = fmaxf(m, e);
  }
  m = fmaxf(m, __shfl_xor(m, 8));
  m = fmaxf(m, __shfl_xor(m, 16));
  m = fmaxf(m, __shfl_xor(m, 32));
  // lane now wants head hB = lane>>3 (channels 2*lane, 2*lane+1)
  int hB = lane >> 3;
  float mh  = __shfl(m, hB);          // lanes 0..7 hold per-head maxes
  float adB = adst[node * 8 + hB];

  const float2* Hv = (const float2*)H;
  float2 acc = make_float2(0.f, 0.f);
  float denom = 0.f;
  for (int i = 0; i < deg; i++){
    int s = col[beg + i];
    float e = asrc[s * 8 + hB] + adB;
    e = e > 0.f ? e : 0.2f * e;
    float ex = expf(e - mh);
    float2 f = Hv[(size_t)s * 64 + lane];
    acc.x = fmaf(ex, f.x, acc.x);
    acc.y = fmaf(ex, f.y, acc.y);
    denom += ex;
  }
  denom += 1e-16f;
  float2 bv = ((const float2*)bias)[lane];
  float ox = acc.x / denom + bv.x;
  float oy = acc.y / denom + bv.y;
  ox = ox > 0.f ? ox : expm1f(ox);   // ELU
  oy = oy > 0.f ? oy : expm1f(oy);
  ((float2*)G)[(size_t)node * 64 + lane] = make_float2(ox, oy);
}

// ---------------- GEMM2: [n,128] @ [128,40] (+0 pad to 48) ----------------
__global__ __launch_bounds__(256)
void gemm2_kernel(const float* __restrict__ X, const float* __restrict__ W,
                  float* __restrict__ H, int n){
  __shared__ float xs[16][132];
  __shared__ float ws[16][48];
  int tid = threadIdx.x;
  int rg = tid >> 3, cg = tid & 7;
  int r0 = rg * 4, c0 = cg * 6;
  int row0 = blockIdx.x * 128;
  float acc[4][6];
  #pragma unroll
  for (int i = 0; i < 4; i++)
    #pragma unroll
    for (int j = 0; j < 6; j++) acc[i][j] = 0.f;

  for (int k0 = 0; k0 < 128; k0 += 16){
    #pragma unroll
    for (int l = 0; l < 3; l++){
      int idx = tid + l * 256;              // 768 = 16*48
      int kk = idx / 48, c = idx % 48;
      ws[kk][c] = (c < 40) ? W[(size_t)(k0 + kk) * 40 + c] : 0.f;
    }
    #pragma unroll
    for (int l = 0; l < 2; l++){
      int f4 = tid + l * 256;
      int row = f4 >> 2, kq = f4 & 3;
      float4 v = make_float4(0.f, 0.f, 0.f, 0.f);
      if (row0 + row < n)
        v = *(const float4*)(X + (size_t)(row0 + row) * 128 + k0 + kq * 4);
      xs[kq*4+0][row] = v.x; xs[kq*4+1][row] = v.y;
      xs[kq*4+2][row] = v.z; xs[kq*4+3][row] = v.w;
    }
    __syncthreads();
    #pragma unroll
    for (int k = 0; k < 16; k++){
      float4 xa = *(const float4*)&xs[k][r0];
      float xr[4] = {xa.x, xa.y, xa.z, xa.w};
      float wr[6];
      #pragma unroll
      for (int j = 0; j < 6; j++) wr[j] = ws[k][c0 + j];
      #pragma unroll
      for (int i = 0; i < 4; i++)
        #pragma unroll
        for (int j = 0; j < 6; j++)
          acc[i][j] = fmaf(xr[i], wr[j], acc[i][j]);
    }
    __syncthreads();
  }
  #pragma unroll
  for (int i = 0; i < 4; i++){
    int r = row0 + r0 + i;
    if (r < n){
      #pragma unroll
      for (int j = 0; j < 6; j++){
        int c = c0 + j;
        if (c < 40) H[(size_t)r * 40 + c] = acc[i][j];
      }
    }
  }
}

// ---------------- att2: wave per node, lanes 0..39 ----------------
__global__ __launch_bounds__(256)
void att2_kernel(const float* __restrict__ H, const float* __restrict__ As,
                 const float* __restrict__ Ad, float* __restrict__ asrc,
                 float* __restrict__ adst, int n){
  int lane = threadIdx.x & 63;
  int node = blockIdx.x * 4 + (threadIdx.x >> 6);
  if (node >= n) return;
  float v = 0.f, a = 0.f, d = 0.f;
  if (lane < 40){
    v = H[(size_t)node * 40 + lane];
    a = As[lane];
    d = Ad[lane];
  }
  float s1 = wave_sum(v * a);
  float s2 = wave_sum(v * d);
  if (lane == 0){ asrc[node] = s1; adst[node] = s2; }
}

// ---------------- agg2 + bias + log_softmax ----------------
__global__ __launch_bounds__(256)
void agg2_kernel(const float* __restrict__ H, const int* __restrict__ offs,
                 const int* __restrict__ cnt, const int* __restrict__ col,
                 const float* __restrict__ asrc, const float* __restrict__ adst,
                 const float* __restrict__ bias, float* __restrict__ out, int n){
  int lane = threadIdx.x & 63;
  int node = blockIdx.x * 4 + (threadIdx.x >> 6);
  if (node >= n) return;
  int beg = offs[node], deg = cnt[node];
  float ad = adst[node];

  float m = -INFINITY;
  for (int i = lane; i < deg; i += 64){
    float e = asrc[col[beg + i]] + ad;
    e = e > 0.f ? e : 0.2f * e;
    m = fmaxf(m, e);
  }
  m = wave_max(m);

  float acc = 0.f, denom = 0.f;
  for (int i = 0; i < deg; i++){
    int s = col[beg + i];
    float e = asrc[s] + ad;
    e = e > 0.f ? e : 0.2f * e;
    float ex = expf(e - m);
    denom += ex;
    if (lane < 40) acc = fmaf(ex, H[(size_t)s * 40 + lane], acc);
  }
  float val = 0.f;
  if (lane < 40) val = acc / (denom + 1e-16f) + bias[lane];

  float mx = wave_max(lane < 40 ? val : -INFINITY);
  float ssum = wave_sum(lane < 40 ? expf(val - mx) : 0.f);
  float ls = logf(ssum);
  if (lane < 40) out[(size_t)node * 40 + lane] = val - mx - ls;
}

// ---------------- launch ----------------
extern "C" void kernel_launch(void* const* d_in, const int* in_sizes, int n_in,
                              void* d_out, int out_size, void* d_ws, size_t ws_size,
                              hipStream_t stream){
  const float* x   = (const float*)d_in[0];
  const int*   ei  = (const int*)d_in[1];
  const float* W1  = (const float*)d_in[2];
  const float* as1 = (const float*)d_in[3];
  const float* ad1 = (const float*)d_in[4];
  const float* b1  = (const float*)d_in[5];
  const float* W2  = (const float*)d_in[6];
  const float* as2 = (const float*)d_in[7];
  const float* ad2 = (const float*)d_in[8];
  const float* b2  = (const float*)d_in[9];
  float* out = (float*)d_out;

  int n = in_sizes[0] / 128;
  int E = in_sizes[1] / 2;
  const int* src = ei;
  const int* dst = ei + E;
  int tot = E + n;

  char* w = (char*)d_ws;
  size_t off = 0;
  auto alloc = [&](size_t bytes){
    size_t r = off; off += (bytes + 255) & ~(size_t)255; return r;
  };
  int*   cnt  = (int*)(w + alloc((size_t)n * 4));
  int*   offs = (int*)(w + alloc((size_t)(n + 1) * 4));
  int*   cur  = (int*)(w + alloc((size_t)n * 4));
  int*   aux  = (int*)(w + alloc(1024));
  int*   col  = (int*)(w + alloc((size_t)tot * 4));
  float* h1   = (float*)(w + alloc((size_t)n * 128 * 4));
  float* g1   = (float*)(w + alloc((size_t)n * 128 * 4));
  float* s1   = (float*)(w + alloc((size_t)n * 8 * 4));
  float* t1   = (float*)(w + alloc((size_t)n * 8 * 4));
  // layer-2 buffers alias layer-1 buffers that are dead after agg1
  float* h2 = h1;   // n*40 <= n*128
  float* s2 = s1;   // n <= n*8
  float* t2 = t1;
  (void)ws_size; (void)n_in; (void)out_size;

  zero_int_kernel<<<(n + 255) / 256, 256, 0, stream>>>(cnt, n);
  count_kernel<<<(tot + 255) / 256, 256, 0, stream>>>(dst, cnt, E, tot);
  int nsb = (n + 1023) / 1024;
  scan_a_kernel<<<nsb, 256, 0, stream>>>(cnt, offs, aux, n);
  scan_b_kernel<<<1, 256, 0, stream>>>(aux, nsb);
  scan_c_kernel<<<(n + 255) / 256, 256, 0, stream>>>(offs, aux, cur, n);
  fill_kernel<<<(tot + 255) / 256, 256, 0, stream>>>(src, dst, cur, col, E, tot);

  gemm1_kernel<<<(n + 127) / 128, 256, 0, stream>>>(x, W1, h1, n);
  att1_kernel<<<(n * 8 + 255) / 256, 256, 0, stream>>>(h1, as1, ad1, s1, t1, n);
  agg1_kernel<<<(n + 3) / 4, 256, 0, stream>>>(h1, offs, cnt, col, s1, t1, b1, g1, n);

  gemm2_kernel<<<(n + 127) / 128, 256, 0, stream>>>(g1, W2, h2, n);
  att2_kernel<<<(n + 3) / 4, 256, 0, stream>>>(h2, as2, ad2, s2, t2, n);
  agg2_kernel<<<(n + 3) / 4, 256, 0, stream>>>(h2, offs, cnt, col, s2, t2, b2, out, n);
}

// Round 2
// 633.698 us; speedup vs baseline: 1.3289x; 1.3289x over previous
//
#include <hip/hip_runtime.h>
#include <math.h>

// GAT 2-layer: N=100K nodes, E=1.6M edges + self loops.
// CSR-by-dst built once, reused for both layers.
// Aggregation: wave per node, flash-style online softmax.
//   Phase A: lane-parallel logits -> ex in per-wave LDS (exp computed once).
//   Phase C: feature gather, unrolled x4 for MLP (memory-level parallelism).
// No __syncthreads in per-wave loops (divergent trip counts across waves).

__device__ __forceinline__ float wave_max(float v){
  #pragma unroll
  for (int m = 1; m < 64; m <<= 1) v = fmaxf(v, __shfl_xor(v, m));
  return v;
}
__device__ __forceinline__ float wave_sum(float v){
  #pragma unroll
  for (int m = 1; m < 64; m <<= 1) v += __shfl_xor(v, m);
  return v;
}
// wave-internal LDS write->read ordering (no cross-wave sync needed)
__device__ __forceinline__ void lds_fence(){
  asm volatile("s_waitcnt lgkmcnt(0)" ::: "memory");
  __builtin_amdgcn_sched_barrier(0);
}

// ---------------- CSR build ----------------

__global__ void zero_int_kernel(int* __restrict__ p, int n){
  int i = blockIdx.x * 256 + threadIdx.x;
  if (i < n) p[i] = 0;
}

__global__ void count_kernel(const int* __restrict__ dst, int* __restrict__ cnt,
                             int E, int tot){
  int i = blockIdx.x * 256 + threadIdx.x;
  if (i >= tot) return;
  int d = (i < E) ? dst[i] : (i - E);   // tail = self loops
  atomicAdd(&cnt[d], 1);
}

__global__ __launch_bounds__(256)
void scan_a_kernel(const int* __restrict__ cnt, int* __restrict__ offs,
                   int* __restrict__ aux, int n){
  __shared__ int ssum[256];
  int tid = threadIdx.x;
  int base = blockIdx.x * 1024;
  int idx = base + tid * 4;
  int4 v = make_int4(0,0,0,0);
  if (idx + 3 < n) v = *(const int4*)(cnt + idx);
  else {
    if (idx     < n) v.x = cnt[idx];
    if (idx + 1 < n) v.y = cnt[idx+1];
    if (idx + 2 < n) v.z = cnt[idx+2];
  }
  int s01 = v.x + v.y;
  int tsum = s01 + v.z + v.w;
  ssum[tid] = tsum;
  __syncthreads();
  #pragma unroll
  for (int d = 1; d < 256; d <<= 1){
    int x = (tid >= d) ? ssum[tid - d] : 0;
    __syncthreads();
    ssum[tid] += x;
    __syncthreads();
  }
  int excl = (tid > 0) ? ssum[tid-1] : 0;
  if (tid == 255) aux[blockIdx.x] = ssum[255];
  if (idx     < n) offs[idx]   = excl;
  if (idx + 1 < n) offs[idx+1] = excl + v.x;
  if (idx + 2 < n) offs[idx+2] = excl + s01;
  if (idx + 3 < n) offs[idx+3] = excl + s01 + v.z;
}

__global__ __launch_bounds__(256)
void scan_b_kernel(int* __restrict__ aux, int nb){
  __shared__ int ssum[256];
  int tid = threadIdx.x;
  int v = (tid < nb) ? aux[tid] : 0;
  ssum[tid] = v;
  __syncthreads();
  #pragma unroll
  for (int d = 1; d < 256; d <<= 1){
    int x = (tid >= d) ? ssum[tid - d] : 0;
    __syncthreads();
    ssum[tid] += x;
    __syncthreads();
  }
  if (tid < nb) aux[tid] = (tid > 0) ? ssum[tid-1] : 0;
}

__global__ void scan_c_kernel(int* __restrict__ offs, const int* __restrict__ aux,
                              int* __restrict__ cur, int n){
  int i = blockIdx.x * 256 + threadIdx.x;
  if (i >= n) return;
  int o = offs[i] + aux[i >> 10];
  offs[i] = o;
  cur[i]  = o;
}

__global__ void fill_kernel(const int* __restrict__ src, const int* __restrict__ dst,
                            int* __restrict__ cur, int* __restrict__ col,
                            int E, int tot){
  int i = blockIdx.x * 256 + threadIdx.x;
  if (i >= tot) return;
  int s, d;
  if (i < E){ s = src[i]; d = dst[i]; } else { s = i - E; d = s; }
  int pos = atomicAdd(&cur[d], 1);
  col[pos] = s;
}

// ---------------- GEMM1: [n,128] @ [128,128] ----------------
__global__ __launch_bounds__(256)
void gemm1_kernel(const float* __restrict__ X, const float* __restrict__ W,
                  float* __restrict__ H, int n){
  __shared__ float xs[16][132];   // transposed: xs[k][row]
  __shared__ float ws[16][128];
  int tid = threadIdx.x;
  int rg = tid >> 4, cg = tid & 15;
  int r0 = rg * 8, c0 = cg * 4;
  int row0 = blockIdx.x * 128;
  float acc[8][8];
  #pragma unroll
  for (int i = 0; i < 8; i++)
    #pragma unroll
    for (int j = 0; j < 8; j++) acc[i][j] = 0.f;

  for (int k0 = 0; k0 < 128; k0 += 16){
    #pragma unroll
    for (int l = 0; l < 2; l++){
      int f4 = tid + l * 256;
      int kk = f4 >> 5, cq = f4 & 31;
      float4 w = *(const float4*)(W + (size_t)(k0 + kk) * 128 + cq * 4);
      *(float4*)&ws[kk][cq * 4] = w;
    }
    #pragma unroll
    for (int l = 0; l < 2; l++){
      int f4 = tid + l * 256;
      int row = f4 >> 2, kq = f4 & 3;
      float4 v = make_float4(0.f, 0.f, 0.f, 0.f);
      if (row0 + row < n)
        v = *(const float4*)(X + (size_t)(row0 + row) * 128 + k0 + kq * 4);
      xs[kq*4+0][row] = v.x; xs[kq*4+1][row] = v.y;
      xs[kq*4+2][row] = v.z; xs[kq*4+3][row] = v.w;
    }
    __syncthreads();
    #pragma unroll
    for (int k = 0; k < 16; k++){
      float4 xa = *(const float4*)&xs[k][r0];
      float4 xb = *(const float4*)&xs[k][r0 + 4];
      float4 wa = *(const float4*)&ws[k][c0];
      float4 wb = *(const float4*)&ws[k][c0 + 64];
      float xr[8] = {xa.x,xa.y,xa.z,xa.w,xb.x,xb.y,xb.z,xb.w};
      float wr[8] = {wa.x,wa.y,wa.z,wa.w,wb.x,wb.y,wb.z,wb.w};
      #pragma unroll
      for (int i = 0; i < 8; i++)
        #pragma unroll
        for (int j = 0; j < 8; j++)
          acc[i][j] = fmaf(xr[i], wr[j], acc[i][j]);
    }
    __syncthreads();
  }
  #pragma unroll
  for (int i = 0; i < 8; i++){
    int r = row0 + r0 + i;
    if (r < n){
      *(float4*)(H + (size_t)r * 128 + c0)
          = make_float4(acc[i][0], acc[i][1], acc[i][2], acc[i][3]);
      *(float4*)(H + (size_t)r * 128 + c0 + 64)
          = make_float4(acc[i][4], acc[i][5], acc[i][6], acc[i][7]);
    }
  }
}

// ---------------- att1 ----------------
__global__ __launch_bounds__(256)
void att1_kernel(const float* __restrict__ H, const float* __restrict__ As,
                 const float* __restrict__ Ad, float* __restrict__ asrc,
                 float* __restrict__ adst, int n){
  __shared__ float sa[128], sd[128];
  int tid = threadIdx.x;
  if (tid < 128){ sa[tid] = As[tid]; sd[tid] = Ad[tid]; }
  __syncthreads();
  int t = blockIdx.x * 256 + tid;
  if (t >= n * 8) return;
  int node = t >> 3, h = t & 7;
  const float* hp = H + (size_t)node * 128 + h * 16;
  float s = 0.f, d = 0.f;
  #pragma unroll
  for (int c = 0; c < 16; c++){
    float v = hp[c];
    s = fmaf(v, sa[h * 16 + c], s);
    d = fmaf(v, sd[h * 16 + c], d);
  }
  asrc[t] = s; adst[t] = d;
}

// ---------------- agg1: wave per node, 8 heads x 16 ch ----------------
// Phase A layout: lane = slot*8+head (iA=lane>>3, hA=lane&7), slots step 8.
// Phase C layout: lane owns channels {2*lane, 2*lane+1}, head hB=lane>>3.
#define CAP1 64
__global__ __launch_bounds__(256)
void agg1_kernel(const float* __restrict__ H, const int* __restrict__ offs,
                 const int* __restrict__ cnt, const int* __restrict__ col,
                 const float* __restrict__ asrc, const float* __restrict__ adst,
                 const float* __restrict__ bias, float* __restrict__ G, int n){
  __shared__ int   scol[4][CAP1];
  __shared__ float sex[4][CAP1][8];
  int lane = threadIdx.x & 63;
  int wid  = threadIdx.x >> 6;
  int node = blockIdx.x * 4 + wid;
  if (node >= n) return;
  int beg = offs[node], deg = cnt[node];

  int hA = lane & 7, iA = lane >> 3;
  int hB = lane >> 3;
  float adA = adst[node * 8 + hA];

  float2 acc = make_float2(0.f, 0.f);
  float m_run = -INFINITY;
  float denomA = 0.f;   // per-lane partial (head hA), rescaled per chunk

  for (int c0 = 0; c0 < deg; c0 += CAP1){
    int cdeg = min(CAP1, deg - c0);
    // phase A: logits in registers (static idx), chunk max per head
    float ev[8];
    float cm = -INFINITY;
    #pragma unroll
    for (int k = 0; k < 8; k++){
      int i = iA + k * 8;
      ev[k] = -INFINITY;
      if (i < cdeg){
        int s = col[beg + c0 + i];
        if (hA == 0) scol[wid][i] = s;
        float e = asrc[s * 8 + hA] + adA;
        e = e > 0.f ? e : 0.2f * e;
        ev[k] = e;
        cm = fmaxf(cm, e);
      }
    }
    cm = fmaxf(cm, __shfl_xor(cm, 8));
    cm = fmaxf(cm, __shfl_xor(cm, 16));
    cm = fmaxf(cm, __shfl_xor(cm, 32));
    float m_new = fmaxf(m_run, cm);
    float scaleA = __expf(m_run - m_new);   // first chunk: exp(-inf)=0
    denomA *= scaleA;
    #pragma unroll
    for (int k = 0; k < 8; k++){
      int i = iA + k * 8;
      if (i < cdeg){
        float ex = __expf(ev[k] - m_new);
        denomA += ex;
        sex[wid][i][hA] = ex;
      }
    }
    m_run = m_new;
    // rescale acc (phase-C layout): lane h (h<8) holds head-h scale
    float scaleB = __shfl(scaleA, hB);
    acc.x *= scaleB; acc.y *= scaleB;
    lds_fence();
    // phase C: gather H rows, unrolled x4
    const float2* Hv = (const float2*)H;
    int i = 0;
    for (; i + 3 < cdeg; i += 4){
      int s0 = scol[wid][i],   s1 = scol[wid][i+1];
      int s2 = scol[wid][i+2], s3 = scol[wid][i+3];
      float x0 = sex[wid][i][hB],   x1 = sex[wid][i+1][hB];
      float x2 = sex[wid][i+2][hB], x3 = sex[wid][i+3][hB];
      float2 f0 = Hv[(size_t)s0 * 64 + lane];
      float2 f1 = Hv[(size_t)s1 * 64 + lane];
      float2 f2 = Hv[(size_t)s2 * 64 + lane];
      float2 f3 = Hv[(size_t)s3 * 64 + lane];
      acc.x = fmaf(x0, f0.x, acc.x); acc.y = fmaf(x0, f0.y, acc.y);
      acc.x = fmaf(x1, f1.x, acc.x); acc.y = fmaf(x1, f1.y, acc.y);
      acc.x = fmaf(x2, f2.x, acc.x); acc.y = fmaf(x2, f2.y, acc.y);
      acc.x = fmaf(x3, f3.x, acc.x); acc.y = fmaf(x3, f3.y, acc.y);
    }
    for (; i < cdeg; i++){
      int s = scol[wid][i];
      float x = sex[wid][i][hB];
      float2 f = Hv[(size_t)s * 64 + lane];
      acc.x = fmaf(x, f.x, acc.x); acc.y = fmaf(x, f.y, acc.y);
    }
  }
  // full per-head denom: reduce partials, move to phase-C layout
  denomA += __shfl_xor(denomA, 8);
  denomA += __shfl_xor(denomA, 16);
  denomA += __shfl_xor(denomA, 32);
  float denomB = __shfl(denomA, hB) + 1e-16f;
  float2 bv = ((const float2*)bias)[lane];
  float ox = acc.x / denomB + bv.x;
  float oy = acc.y / denomB + bv.y;
  ox = ox > 0.f ? ox : expm1f(ox);   // ELU
  oy = oy > 0.f ? oy : expm1f(oy);
  ((float2*)G)[(size_t)node * 64 + lane] = make_float2(ox, oy);
}

// ---------------- GEMM2: [n,128] @ [128,40] ----------------
__global__ __launch_bounds__(256)
void gemm2_kernel(const float* __restrict__ X, const float* __restrict__ W,
                  float* __restrict__ H, int n){
  __shared__ float xs[16][132];
  __shared__ float ws[16][48];
  int tid = threadIdx.x;
  int rg = tid >> 3, cg = tid & 7;
  int r0 = rg * 4, c0 = cg * 6;
  int row0 = blockIdx.x * 128;
  float acc[4][6];
  #pragma unroll
  for (int i = 0; i < 4; i++)
    #pragma unroll
    for (int j = 0; j < 6; j++) acc[i][j] = 0.f;

  for (int k0 = 0; k0 < 128; k0 += 16){
    #pragma unroll
    for (int l = 0; l < 3; l++){
      int idx = tid + l * 256;
      int kk = idx / 48, c = idx % 48;
      ws[kk][c] = (c < 40) ? W[(size_t)(k0 + kk) * 40 + c] : 0.f;
    }
    #pragma unroll
    for (int l = 0; l < 2; l++){
      int f4 = tid + l * 256;
      int row = f4 >> 2, kq = f4 & 3;
      float4 v = make_float4(0.f, 0.f, 0.f, 0.f);
      if (row0 + row < n)
        v = *(const float4*)(X + (size_t)(row0 + row) * 128 + k0 + kq * 4);
      xs[kq*4+0][row] = v.x; xs[kq*4+1][row] = v.y;
      xs[kq*4+2][row] = v.z; xs[kq*4+3][row] = v.w;
    }
    __syncthreads();
    #pragma unroll
    for (int k = 0; k < 16; k++){
      float4 xa = *(const float4*)&xs[k][r0];
      float xr[4] = {xa.x, xa.y, xa.z, xa.w};
      float wr[6];
      #pragma unroll
      for (int j = 0; j < 6; j++) wr[j] = ws[k][c0 + j];
      #pragma unroll
      for (int i = 0; i < 4; i++)
        #pragma unroll
        for (int j = 0; j < 6; j++)
          acc[i][j] = fmaf(xr[i], wr[j], acc[i][j]);
    }
    __syncthreads();
  }
  #pragma unroll
  for (int i = 0; i < 4; i++){
    int r = row0 + r0 + i;
    if (r < n){
      #pragma unroll
      for (int j = 0; j < 6; j++){
        int c = c0 + j;
        if (c < 40) H[(size_t)r * 40 + c] = acc[i][j];
      }
    }
  }
}

// ---------------- att2 ----------------
__global__ __launch_bounds__(256)
void att2_kernel(const float* __restrict__ H, const float* __restrict__ As,
                 const float* __restrict__ Ad, float* __restrict__ asrc,
                 float* __restrict__ adst, int n){
  int lane = threadIdx.x & 63;
  int node = blockIdx.x * 4 + (threadIdx.x >> 6);
  if (node >= n) return;
  float v = 0.f, a = 0.f, d = 0.f;
  if (lane < 40){
    v = H[(size_t)node * 40 + lane];
    a = As[lane];
    d = Ad[lane];
  }
  float s1 = wave_sum(v * a);
  float s2 = wave_sum(v * d);
  if (lane == 0){ asrc[node] = s1; adst[node] = s2; }
}

// ---------------- agg2 + bias + log_softmax ----------------
#define CAP2 128
__global__ __launch_bounds__(256)
void agg2_kernel(const float* __restrict__ H, const int* __restrict__ offs,
                 const int* __restrict__ cnt, const int* __restrict__ col,
                 const float* __restrict__ asrc, const float* __restrict__ adst,
                 const float* __restrict__ bias, float* __restrict__ out, int n){
  __shared__ int   scol[4][CAP2];
  __shared__ float sex[4][CAP2];
  int lane = threadIdx.x & 63;
  int wid  = threadIdx.x >> 6;
  int node = blockIdx.x * 4 + wid;
  if (node >= n) return;
  int beg = offs[node], deg = cnt[node];
  float ad = adst[node];

  float acc = 0.f;
  float m_run = -INFINITY;
  float denom = 0.f;           // wave-uniform running denominator

  for (int c0 = 0; c0 < deg; c0 += CAP2){
    int cdeg = min(CAP2, deg - c0);
    float ev[2];
    float cm = -INFINITY;
    #pragma unroll
    for (int k = 0; k < 2; k++){
      int i = lane + k * 64;
      ev[k] = -INFINITY;
      if (i < cdeg){
        int s = col[beg + c0 + i];
        scol[wid][i] = s;
        float e = asrc[s] + ad;
        e = e > 0.f ? e : 0.2f * e;
        ev[k] = e;
        cm = fmaxf(cm, e);
      }
    }
    cm = wave_max(cm);
    float m_new = fmaxf(m_run, cm);
    float scale = __expf(m_run - m_new);
    float part = 0.f;
    #pragma unroll
    for (int k = 0; k < 2; k++){
      int i = lane + k * 64;
      if (i < cdeg){
        float ex = __expf(ev[k] - m_new);
        part += ex;
        sex[wid][i] = ex;
      }
    }
    denom = denom * scale + wave_sum(part);
    acc *= scale;
    m_run = m_new;
    lds_fence();
    int i = 0;
    for (; i + 3 < cdeg; i += 4){
      int s0 = scol[wid][i],   s1 = scol[wid][i+1];
      int s2 = scol[wid][i+2], s3 = scol[wid][i+3];
      float x0 = sex[wid][i],   x1 = sex[wid][i+1];
      float x2 = sex[wid][i+2], x3 = sex[wid][i+3];
      float f0 = 0.f, f1 = 0.f, f2 = 0.f, f3 = 0.f;
      if (lane < 40){
        f0 = H[(size_t)s0 * 40 + lane];
        f1 = H[(size_t)s1 * 40 + lane];
        f2 = H[(size_t)s2 * 40 + lane];
        f3 = H[(size_t)s3 * 40 + lane];
      }
      acc = fmaf(x0, f0, acc);
      acc = fmaf(x1, f1, acc);
      acc = fmaf(x2, f2, acc);
      acc = fmaf(x3, f3, acc);
    }
    for (; i < cdeg; i++){
      int s = scol[wid][i];
      float x = sex[wid][i];
      float f = (lane < 40) ? H[(size_t)s * 40 + lane] : 0.f;
      acc = fmaf(x, f, acc);
    }
  }
  float val = 0.f;
  if (lane < 40) val = acc / (denom + 1e-16f) + bias[lane];

  float mx = wave_max(lane < 40 ? val : -INFINITY);
  float ssum = wave_sum(lane < 40 ? __expf(val - mx) : 0.f);
  float ls = logf(ssum);
  if (lane < 40) out[(size_t)node * 40 + lane] = val - mx - ls;
}

// ---------------- launch ----------------
extern "C" void kernel_launch(void* const* d_in, const int* in_sizes, int n_in,
                              void* d_out, int out_size, void* d_ws, size_t ws_size,
                              hipStream_t stream){
  const float* x   = (const float*)d_in[0];
  const int*   ei  = (const int*)d_in[1];
  const float* W1  = (const float*)d_in[2];
  const float* as1 = (const float*)d_in[3];
  const float* ad1 = (const float*)d_in[4];
  const float* b1  = (const float*)d_in[5];
  const float* W2  = (const float*)d_in[6];
  const float* as2 = (const float*)d_in[7];
  const float* ad2 = (const float*)d_in[8];
  const float* b2  = (const float*)d_in[9];
  float* out = (float*)d_out;

  int n = in_sizes[0] / 128;
  int E = in_sizes[1] / 2;
  const int* src = ei;
  const int* dst = ei + E;
  int tot = E + n;

  char* w = (char*)d_ws;
  size_t off = 0;
  auto alloc = [&](size_t bytes){
    size_t r = off; off += (bytes + 255) & ~(size_t)255; return r;
  };
  int*   cnt  = (int*)(w + alloc((size_t)n * 4));
  int*   offs = (int*)(w + alloc((size_t)(n + 1) * 4));
  int*   cur  = (int*)(w + alloc((size_t)n * 4));
  int*   aux  = (int*)(w + alloc(1024));
  int*   col  = (int*)(w + alloc((size_t)tot * 4));
  float* h1   = (float*)(w + alloc((size_t)n * 128 * 4));
  float* g1   = (float*)(w + alloc((size_t)n * 128 * 4));
  float* s1   = (float*)(w + alloc((size_t)n * 8 * 4));
  float* t1   = (float*)(w + alloc((size_t)n * 8 * 4));
  float* h2 = h1;   // layer-2 aliases (h1 dead after agg1)
  float* s2 = s1;
  float* t2 = t1;
  (void)ws_size; (void)n_in; (void)out_size;

  zero_int_kernel<<<(n + 255) / 256, 256, 0, stream>>>(cnt, n);
  count_kernel<<<(tot + 255) / 256, 256, 0, stream>>>(dst, cnt, E, tot);
  int nsb = (n + 1023) / 1024;
  scan_a_kernel<<<nsb, 256, 0, stream>>>(cnt, offs, aux, n);
  scan_b_kernel<<<1, 256, 0, stream>>>(aux, nsb);
  scan_c_kernel<<<(n + 255) / 256, 256, 0, stream>>>(offs, aux, cur, n);
  fill_kernel<<<(tot + 255) / 256, 256, 0, stream>>>(src, dst, cur, col, E, tot);

  gemm1_kernel<<<(n + 127) / 128, 256, 0, stream>>>(x, W1, h1, n);
  att1_kernel<<<(n * 8 + 255) / 256, 256, 0, stream>>>(h1, as1, ad1, s1, t1, n);
  agg1_kernel<<<(n + 3) / 4, 256, 0, stream>>>(h1, offs, cnt, col, s1, t1, b1, g1, n);

  gemm2_kernel<<<(n + 127) / 128, 256, 0, stream>>>(g1, W2, h2, n);
  att2_kernel<<<(n + 3) / 4, 256, 0, stream>>>(h2, as2, ad2, s2, t2, n);
  agg2_kernel<<<(n + 3) / 4, 256, 0, stream>>>(h2, offs, cnt, col, s2, t2, b2, out, n);
}

// Round 4
// 628.676 us; speedup vs baseline: 1.3395x; 1.0080x over previous
//
#include <hip/hip_runtime.h>
#include <math.h>

// GAT 2-layer: N=100K nodes, E=1.6M edges + self loops.
// CSR-by-dst built once, reused for both layers.
// Aggregation: wave per node, flash-style online softmax.
// Feature arrays gathered per-edge are stored bf16 (fp32 accumulate):
// halves the gather traffic that round-2 counters showed as the bottleneck
// (agg1: 487MB L2-miss fetch @3.4TB/s). Logits/softmax/accum stay fp32.
// NOTE: round-3 submission hit an infra failure (container died twice);
// this is an identical resubmission to measure the bf16-gather theory.

__device__ __forceinline__ float wave_max(float v){
  #pragma unroll
  for (int m = 1; m < 64; m <<= 1) v = fmaxf(v, __shfl_xor(v, m));
  return v;
}
__device__ __forceinline__ float wave_sum(float v){
  #pragma unroll
  for (int m = 1; m < 64; m <<= 1) v += __shfl_xor(v, m);
  return v;
}
// wave-internal LDS write->read ordering (no cross-wave sync needed)
__device__ __forceinline__ void lds_fence(){
  asm volatile("s_waitcnt lgkmcnt(0)" ::: "memory");
  __builtin_amdgcn_sched_barrier(0);
}

// bf16 helpers (RNE pack, shift unpack)
__device__ __forceinline__ unsigned short f2bf(float f){
  unsigned int u = __float_as_uint(f);
  u += 0x7FFFu + ((u >> 16) & 1u);
  return (unsigned short)(u >> 16);
}
__device__ __forceinline__ float bf2f(unsigned short b){
  return __uint_as_float(((unsigned int)b) << 16);
}
__device__ __forceinline__ float2 bfpair(unsigned int u){
  float2 r;
  r.x = __uint_as_float(u << 16);
  r.y = __uint_as_float(u & 0xFFFF0000u);
  return r;
}

// ---------------- CSR build ----------------

__global__ void init_cnt_kernel(int* __restrict__ p, int n){
  int i = blockIdx.x * 256 + threadIdx.x;
  if (i < n) p[i] = 1;   // self-loop pre-counted
}

__global__ void count_kernel(const int* __restrict__ dst, int* __restrict__ cnt,
                             int E){
  int i = blockIdx.x * 256 + threadIdx.x;
  if (i >= E) return;
  atomicAdd(&cnt[dst[i]], 1);
}

__global__ __launch_bounds__(256)
void scan_a_kernel(const int* __restrict__ cnt, int* __restrict__ offs,
                   int* __restrict__ aux, int n){
  __shared__ int ssum[256];
  int tid = threadIdx.x;
  int base = blockIdx.x * 1024;
  int idx = base + tid * 4;
  int4 v = make_int4(0,0,0,0);
  if (idx + 3 < n) v = *(const int4*)(cnt + idx);
  else {
    if (idx     < n) v.x = cnt[idx];
    if (idx + 1 < n) v.y = cnt[idx+1];
    if (idx + 2 < n) v.z = cnt[idx+2];
  }
  int s01 = v.x + v.y;
  int tsum = s01 + v.z + v.w;
  ssum[tid] = tsum;
  __syncthreads();
  #pragma unroll
  for (int d = 1; d < 256; d <<= 1){
    int x = (tid >= d) ? ssum[tid - d] : 0;
    __syncthreads();
    ssum[tid] += x;
    __syncthreads();
  }
  int excl = (tid > 0) ? ssum[tid-1] : 0;
  if (tid == 255) aux[blockIdx.x] = ssum[255];
  if (idx     < n) offs[idx]   = excl;
  if (idx + 1 < n) offs[idx+1] = excl + v.x;
  if (idx + 2 < n) offs[idx+2] = excl + s01;
  if (idx + 3 < n) offs[idx+3] = excl + s01 + v.z;
}

__global__ __launch_bounds__(256)
void scan_b_kernel(int* __restrict__ aux, int nb){
  __shared__ int ssum[256];
  int tid = threadIdx.x;
  int v = (tid < nb) ? aux[tid] : 0;
  ssum[tid] = v;
  __syncthreads();
  #pragma unroll
  for (int d = 1; d < 256; d <<= 1){
    int x = (tid >= d) ? ssum[tid - d] : 0;
    __syncthreads();
    ssum[tid] += x;
    __syncthreads();
  }
  if (tid < nb) aux[tid] = (tid > 0) ? ssum[tid-1] : 0;
}

__global__ void scan_c_kernel(int* __restrict__ offs, const int* __restrict__ aux,
                              int* __restrict__ cur, int n){
  int i = blockIdx.x * 256 + threadIdx.x;
  if (i >= n) return;
  int o = offs[i] + aux[i >> 10];
  offs[i] = o;
  cur[i]  = o;
}

__global__ void fill_kernel(const int* __restrict__ src, const int* __restrict__ dst,
                            int* __restrict__ cur, int* __restrict__ col,
                            int E, int tot){
  int i = blockIdx.x * 256 + threadIdx.x;
  if (i >= tot) return;
  int s, d;
  if (i < E){ s = src[i]; d = dst[i]; } else { s = i - E; d = s; }
  int pos = atomicAdd(&cur[d], 1);
  col[pos] = s;
}

// ---------------- GEMM1: [n,128]fp32 @ [128,128]fp32 -> bf16 ----------------
__global__ __launch_bounds__(256)
void gemm1_kernel(const float* __restrict__ X, const float* __restrict__ W,
                  unsigned short* __restrict__ Hb, int n){
  __shared__ float xs[16][132];   // transposed: xs[k][row]
  __shared__ float ws[16][128];
  int tid = threadIdx.x;
  int rg = tid >> 4, cg = tid & 15;
  int r0 = rg * 8, c0 = cg * 4;
  int row0 = blockIdx.x * 128;
  float acc[8][8];
  #pragma unroll
  for (int i = 0; i < 8; i++)
    #pragma unroll
    for (int j = 0; j < 8; j++) acc[i][j] = 0.f;

  for (int k0 = 0; k0 < 128; k0 += 16){
    #pragma unroll
    for (int l = 0; l < 2; l++){
      int f4 = tid + l * 256;
      int kk = f4 >> 5, cq = f4 & 31;
      float4 w = *(const float4*)(W + (size_t)(k0 + kk) * 128 + cq * 4);
      *(float4*)&ws[kk][cq * 4] = w;
    }
    #pragma unroll
    for (int l = 0; l < 2; l++){
      int f4 = tid + l * 256;
      int row = f4 >> 2, kq = f4 & 3;
      float4 v = make_float4(0.f, 0.f, 0.f, 0.f);
      if (row0 + row < n)
        v = *(const float4*)(X + (size_t)(row0 + row) * 128 + k0 + kq * 4);
      xs[kq*4+0][row] = v.x; xs[kq*4+1][row] = v.y;
      xs[kq*4+2][row] = v.z; xs[kq*4+3][row] = v.w;
    }
    __syncthreads();
    #pragma unroll
    for (int k = 0; k < 16; k++){
      float4 xa = *(const float4*)&xs[k][r0];
      float4 xb = *(const float4*)&xs[k][r0 + 4];
      float4 wa = *(const float4*)&ws[k][c0];
      float4 wb = *(const float4*)&ws[k][c0 + 64];
      float xr[8] = {xa.x,xa.y,xa.z,xa.w,xb.x,xb.y,xb.z,xb.w};
      float wr[8] = {wa.x,wa.y,wa.z,wa.w,wb.x,wb.y,wb.z,wb.w};
      #pragma unroll
      for (int i = 0; i < 8; i++)
        #pragma unroll
        for (int j = 0; j < 8; j++)
          acc[i][j] = fmaf(xr[i], wr[j], acc[i][j]);
    }
    __syncthreads();
  }
  #pragma unroll
  for (int i = 0; i < 8; i++){
    int r = row0 + r0 + i;
    if (r < n){
      ushort4 a4, b4;
      a4.x = f2bf(acc[i][0]); a4.y = f2bf(acc[i][1]);
      a4.z = f2bf(acc[i][2]); a4.w = f2bf(acc[i][3]);
      b4.x = f2bf(acc[i][4]); b4.y = f2bf(acc[i][5]);
      b4.z = f2bf(acc[i][6]); b4.w = f2bf(acc[i][7]);
      *(ushort4*)(Hb + (size_t)r * 128 + c0)      = a4;
      *(ushort4*)(Hb + (size_t)r * 128 + c0 + 64) = b4;
    }
  }
}

// ---------------- att1: bf16 input ----------------
__global__ __launch_bounds__(256)
void att1_kernel(const unsigned short* __restrict__ Hb, const float* __restrict__ As,
                 const float* __restrict__ Ad, float* __restrict__ asrc,
                 float* __restrict__ adst, int n){
  __shared__ float sa[128], sd[128];
  int tid = threadIdx.x;
  if (tid < 128){ sa[tid] = As[tid]; sd[tid] = Ad[tid]; }
  __syncthreads();
  int t = blockIdx.x * 256 + tid;
  if (t >= n * 8) return;
  int node = t >> 3, h = t & 7;
  const uint4* hp = (const uint4*)(Hb + (size_t)node * 128 + h * 16);
  uint4 u0 = hp[0], u1 = hp[1];
  unsigned int w[8] = {u0.x,u0.y,u0.z,u0.w,u1.x,u1.y,u1.z,u1.w};
  float s = 0.f, d = 0.f;
  #pragma unroll
  for (int q = 0; q < 8; q++){
    float2 p = bfpair(w[q]);
    s = fmaf(p.x, sa[h*16 + 2*q],     s);
    s = fmaf(p.y, sa[h*16 + 2*q + 1], s);
    d = fmaf(p.x, sd[h*16 + 2*q],     d);
    d = fmaf(p.y, sd[h*16 + 2*q + 1], d);
  }
  asrc[t] = s; adst[t] = d;
}

// ---------------- agg1: wave per node, 8 heads x 16 ch, bf16 gather --------
#define CAP1 64
__global__ __launch_bounds__(256)
void agg1_kernel(const unsigned short* __restrict__ Hb, const int* __restrict__ offs,
                 const int* __restrict__ cnt, const int* __restrict__ col,
                 const float* __restrict__ asrc, const float* __restrict__ adst,
                 const float* __restrict__ bias, float* __restrict__ G, int n){
  __shared__ int   scol[4][CAP1];
  __shared__ float sex[4][CAP1][8];
  int lane = threadIdx.x & 63;
  int wid  = threadIdx.x >> 6;
  int node = blockIdx.x * 4 + wid;
  if (node >= n) return;
  int beg = offs[node], deg = cnt[node];

  int hA = lane & 7, iA = lane >> 3;
  int hB = lane >> 3;
  float adA = adst[node * 8 + hA];

  float2 acc = make_float2(0.f, 0.f);
  float m_run = -INFINITY;
  float denomA = 0.f;   // per-lane partial (head hA), rescaled per chunk

  for (int c0 = 0; c0 < deg; c0 += CAP1){
    int cdeg = min(CAP1, deg - c0);
    // phase A: logits in registers (static idx), chunk max per head
    float ev[8];
    float cm = -INFINITY;
    #pragma unroll
    for (int k = 0; k < 8; k++){
      int i = iA + k * 8;
      ev[k] = -INFINITY;
      if (i < cdeg){
        int s = col[beg + c0 + i];
        if (hA == 0) scol[wid][i] = s;
        float e = asrc[s * 8 + hA] + adA;
        e = e > 0.f ? e : 0.2f * e;
        ev[k] = e;
        cm = fmaxf(cm, e);
      }
    }
    cm = fmaxf(cm, __shfl_xor(cm, 8));
    cm = fmaxf(cm, __shfl_xor(cm, 16));
    cm = fmaxf(cm, __shfl_xor(cm, 32));
    float m_new = fmaxf(m_run, cm);
    float scaleA = __expf(m_run - m_new);   // first chunk: exp(-inf)=0
    denomA *= scaleA;
    #pragma unroll
    for (int k = 0; k < 8; k++){
      int i = iA + k * 8;
      if (i < cdeg){
        float ex = __expf(ev[k] - m_new);
        denomA += ex;
        sex[wid][i][hA] = ex;
      }
    }
    m_run = m_new;
    float scaleB = __shfl(scaleA, hB);
    acc.x *= scaleB; acc.y *= scaleB;
    lds_fence();
    // phase C: gather bf16 rows (4B/lane), unrolled x8 for MLP
    const unsigned int* Hu = (const unsigned int*)Hb;
    int i = 0;
    for (; i + 7 < cdeg; i += 8){
      int ss[8]; float xx[8]; unsigned int uu[8];
      #pragma unroll
      for (int k = 0; k < 8; k++){
        ss[k] = scol[wid][i + k];
        xx[k] = sex[wid][i + k][hB];
      }
      #pragma unroll
      for (int k = 0; k < 8; k++)
        uu[k] = Hu[(size_t)ss[k] * 64 + lane];
      #pragma unroll
      for (int k = 0; k < 8; k++){
        float2 f = bfpair(uu[k]);
        acc.x = fmaf(xx[k], f.x, acc.x);
        acc.y = fmaf(xx[k], f.y, acc.y);
      }
    }
    for (; i < cdeg; i++){
      int s = scol[wid][i];
      float x = sex[wid][i][hB];
      float2 f = bfpair(Hu[(size_t)s * 64 + lane]);
      acc.x = fmaf(x, f.x, acc.x);
      acc.y = fmaf(x, f.y, acc.y);
    }
  }
  denomA += __shfl_xor(denomA, 8);
  denomA += __shfl_xor(denomA, 16);
  denomA += __shfl_xor(denomA, 32);
  float denomB = __shfl(denomA, hB) + 1e-16f;
  float2 bv = ((const float2*)bias)[lane];
  float ox = acc.x / denomB + bv.x;
  float oy = acc.y / denomB + bv.y;
  ox = ox > 0.f ? ox : expm1f(ox);   // ELU
  oy = oy > 0.f ? oy : expm1f(oy);
  ((float2*)G)[(size_t)node * 64 + lane] = make_float2(ox, oy);
}

// ---------------- GEMM2: [n,128]fp32 @ [128,40] -> bf16 ----------------
__global__ __launch_bounds__(256)
void gemm2_kernel(const float* __restrict__ X, const float* __restrict__ W,
                  unsigned short* __restrict__ Hb, int n){
  __shared__ float xs[16][132];
  __shared__ float ws[16][48];
  int tid = threadIdx.x;
  int rg = tid >> 3, cg = tid & 7;
  int r0 = rg * 4, c0 = cg * 6;
  int row0 = blockIdx.x * 128;
  float acc[4][6];
  #pragma unroll
  for (int i = 0; i < 4; i++)
    #pragma unroll
    for (int j = 0; j < 6; j++) acc[i][j] = 0.f;

  for (int k0 = 0; k0 < 128; k0 += 16){
    #pragma unroll
    for (int l = 0; l < 3; l++){
      int idx = tid + l * 256;
      int kk = idx / 48, c = idx % 48;
      ws[kk][c] = (c < 40) ? W[(size_t)(k0 + kk) * 40 + c] : 0.f;
    }
    #pragma unroll
    for (int l = 0; l < 2; l++){
      int f4 = tid + l * 256;
      int row = f4 >> 2, kq = f4 & 3;
      float4 v = make_float4(0.f, 0.f, 0.f, 0.f);
      if (row0 + row < n)
        v = *(const float4*)(X + (size_t)(row0 + row) * 128 + k0 + kq * 4);
      xs[kq*4+0][row] = v.x; xs[kq*4+1][row] = v.y;
      xs[kq*4+2][row] = v.z; xs[kq*4+3][row] = v.w;
    }
    __syncthreads();
    #pragma unroll
    for (int k = 0; k < 16; k++){
      float4 xa = *(const float4*)&xs[k][r0];
      float xr[4] = {xa.x, xa.y, xa.z, xa.w};
      float wr[6];
      #pragma unroll
      for (int j = 0; j < 6; j++) wr[j] = ws[k][c0 + j];
      #pragma unroll
      for (int i = 0; i < 4; i++)
        #pragma unroll
        for (int j = 0; j < 6; j++)
          acc[i][j] = fmaf(xr[i], wr[j], acc[i][j]);
    }
    __syncthreads();
  }
  #pragma unroll
  for (int i = 0; i < 4; i++){
    int r = row0 + r0 + i;
    if (r < n){
      #pragma unroll
      for (int j = 0; j < 6; j++){
        int c = c0 + j;
        if (c < 40) Hb[(size_t)r * 40 + c] = f2bf(acc[i][j]);
      }
    }
  }
}

// ---------------- att2: bf16 input ----------------
__global__ __launch_bounds__(256)
void att2_kernel(const unsigned short* __restrict__ Hb, const float* __restrict__ As,
                 const float* __restrict__ Ad, float* __restrict__ asrc,
                 float* __restrict__ adst, int n){
  int lane = threadIdx.x & 63;
  int node = blockIdx.x * 4 + (threadIdx.x >> 6);
  if (node >= n) return;
  float v = 0.f, a = 0.f, d = 0.f;
  if (lane < 40){
    v = bf2f(Hb[(size_t)node * 40 + lane]);
    a = As[lane];
    d = Ad[lane];
  }
  float s1 = wave_sum(v * a);
  float s2 = wave_sum(v * d);
  if (lane == 0){ asrc[node] = s1; adst[node] = s2; }
}

// ---------------- agg2 + bias + log_softmax, bf16 gather ----------------
#define CAP2 128
__global__ __launch_bounds__(256)
void agg2_kernel(const unsigned short* __restrict__ Hb, const int* __restrict__ offs,
                 const int* __restrict__ cnt, const int* __restrict__ col,
                 const float* __restrict__ asrc, const float* __restrict__ adst,
                 const float* __restrict__ bias, float* __restrict__ out, int n){
  __shared__ int   scol[4][CAP2];
  __shared__ float sex[4][CAP2];
  int lane = threadIdx.x & 63;
  int wid  = threadIdx.x >> 6;
  int node = blockIdx.x * 4 + wid;
  if (node >= n) return;
  int beg = offs[node], deg = cnt[node];
  float ad = adst[node];

  float acc = 0.f;
  float m_run = -INFINITY;
  float denom = 0.f;

  for (int c0 = 0; c0 < deg; c0 += CAP2){
    int cdeg = min(CAP2, deg - c0);
    float ev[2];
    float cm = -INFINITY;
    #pragma unroll
    for (int k = 0; k < 2; k++){
      int i = lane + k * 64;
      ev[k] = -INFINITY;
      if (i < cdeg){
        int s = col[beg + c0 + i];
        scol[wid][i] = s;
        float e = asrc[s] + ad;
        e = e > 0.f ? e : 0.2f * e;
        ev[k] = e;
        cm = fmaxf(cm, e);
      }
    }
    cm = wave_max(cm);
    float m_new = fmaxf(m_run, cm);
    float scale = __expf(m_run - m_new);
    float part = 0.f;
    #pragma unroll
    for (int k = 0; k < 2; k++){
      int i = lane + k * 64;
      if (i < cdeg){
        float ex = __expf(ev[k] - m_new);
        part += ex;
        sex[wid][i] = ex;
      }
    }
    denom = denom * scale + wave_sum(part);
    acc *= scale;
    m_run = m_new;
    lds_fence();
    int i = 0;
    for (; i + 7 < cdeg; i += 8){
      int ss[8]; float xx[8]; float ff[8];
      #pragma unroll
      for (int k = 0; k < 8; k++){
        ss[k] = scol[wid][i + k];
        xx[k] = sex[wid][i + k];
      }
      #pragma unroll
      for (int k = 0; k < 8; k++)
        ff[k] = (lane < 40) ? bf2f(Hb[(size_t)ss[k] * 40 + lane]) : 0.f;
      #pragma unroll
      for (int k = 0; k < 8; k++)
        acc = fmaf(xx[k], ff[k], acc);
    }
    for (; i < cdeg; i++){
      int s = scol[wid][i];
      float x = sex[wid][i];
      float f = (lane < 40) ? bf2f(Hb[(size_t)s * 40 + lane]) : 0.f;
      acc = fmaf(x, f, acc);
    }
  }
  float val = 0.f;
  if (lane < 40) val = acc / (denom + 1e-16f) + bias[lane];

  float mx = wave_max(lane < 40 ? val : -INFINITY);
  float ssum = wave_sum(lane < 40 ? __expf(val - mx) : 0.f);
  float ls = logf(ssum);
  if (lane < 40) out[(size_t)node * 40 + lane] = val - mx - ls;
}

// ---------------- launch ----------------
extern "C" void kernel_launch(void* const* d_in, const int* in_sizes, int n_in,
                              void* d_out, int out_size, void* d_ws, size_t ws_size,
                              hipStream_t stream){
  const float* x   = (const float*)d_in[0];
  const int*   ei  = (const int*)d_in[1];
  const float* W1  = (const float*)d_in[2];
  const float* as1 = (const float*)d_in[3];
  const float* ad1 = (const float*)d_in[4];
  const float* b1  = (const float*)d_in[5];
  const float* W2  = (const float*)d_in[6];
  const float* as2 = (const float*)d_in[7];
  const float* ad2 = (const float*)d_in[8];
  const float* b2  = (const float*)d_in[9];
  float* out = (float*)d_out;

  int n = in_sizes[0] / 128;
  int E = in_sizes[1] / 2;
  const int* src = ei;
  const int* dst = ei + E;
  int tot = E + n;

  char* w = (char*)d_ws;
  size_t off = 0;
  auto alloc = [&](size_t bytes){
    size_t r = off; off += (bytes + 255) & ~(size_t)255; return r;
  };
  int*   cnt  = (int*)(w + alloc((size_t)n * 4));
  int*   offs = (int*)(w + alloc((size_t)(n + 1) * 4));
  int*   cur  = (int*)(w + alloc((size_t)n * 4));
  int*   aux  = (int*)(w + alloc(1024));
  int*   col  = (int*)(w + alloc((size_t)tot * 4));
  unsigned short* h1b = (unsigned short*)(w + alloc((size_t)n * 128 * 2));
  float* g1   = (float*)(w + alloc((size_t)n * 128 * 4));
  float* s1   = (float*)(w + alloc((size_t)n * 8 * 4));
  float* t1   = (float*)(w + alloc((size_t)n * 8 * 4));
  unsigned short* h2b = h1b;   // layer-2 aliases (h1b dead after agg1)
  float* s2 = s1;
  float* t2 = t1;
  (void)ws_size; (void)n_in; (void)out_size;

  init_cnt_kernel<<<(n + 255) / 256, 256, 0, stream>>>(cnt, n);
  count_kernel<<<(E + 255) / 256, 256, 0, stream>>>(dst, cnt, E);
  int nsb = (n + 1023) / 1024;
  scan_a_kernel<<<nsb, 256, 0, stream>>>(cnt, offs, aux, n);
  scan_b_kernel<<<1, 256, 0, stream>>>(aux, nsb);
  scan_c_kernel<<<(n + 255) / 256, 256, 0, stream>>>(offs, aux, cur, n);
  fill_kernel<<<(tot + 255) / 256, 256, 0, stream>>>(src, dst, cur, col, E, tot);

  gemm1_kernel<<<(n + 127) / 128, 256, 0, stream>>>(x, W1, h1b, n);
  att1_kernel<<<(n * 8 + 255) / 256, 256, 0, stream>>>(h1b, as1, ad1, s1, t1, n);
  agg1_kernel<<<(n + 3) / 4, 256, 0, stream>>>(h1b, offs, cnt, col, s1, t1, b1, g1, n);

  gemm2_kernel<<<(n + 127) / 128, 256, 0, stream>>>(g1, W2, h2b, n);
  att2_kernel<<<(n + 3) / 4, 256, 0, stream>>>(h2b, as2, ad2, s2, t2, n);
  agg2_kernel<<<(n + 3) / 4, 256, 0, stream>>>(h2b, offs, cnt, col, s2, t2, b2, out, n);
}